// Round 1
// baseline (1061.978 us; speedup 1.0000x reference)
//
#include <hip/hip_runtime.h>

#define ALPHA_V 0.99f
#define TH_HID 0.1f
#define TH_LAST 1.0e5f

// GEMM: Z[b,o,t] = sum_i W[o,i] * X[b,i,t]
// X: [B, Cin, T] (t contiguous), W: [Cout, Cin] row-major, Z: [B, Cout, T]
// grid: (ceil(T/BT), ceil(Cout/BO), B), block: 256 threads
// thread tile: (BO/16) o-values x 4 t-values
template<int BO, int BT, int BK>
__global__ __launch_bounds__(256) void gemm_bot(
    const float* __restrict__ X, const float* __restrict__ W,
    float* __restrict__ Z, int B, int Cin, int Cout, int T)
{
    constexpr int OJ = BO / 16;     // o-values per thread
    __shared__ float Xs[BK][BT];
    __shared__ float Ws[BO][BK + 1];   // +1 pad: kill bank conflicts

    const int b = blockIdx.z;
    const int o_base = blockIdx.y * BO;
    const int t_base = blockIdx.x * BT;
    const int tid = threadIdx.x;
    const int tt = tid & 15;        // t-group: 4 consecutive t each
    const int to = tid >> 4;        // o-group: OJ consecutive o each

    float acc[OJ][4];
#pragma unroll
    for (int j = 0; j < OJ; ++j)
#pragma unroll
        for (int u = 0; u < 4; ++u) acc[j][u] = 0.f;

    const float* Xb = X + (size_t)b * Cin * T;

    for (int k0 = 0; k0 < Cin; k0 += BK) {
        // stage X tile [BK][BT]  (coalesced over t)
#pragma unroll
        for (int f = tid; f < BK * BT; f += 256) {
            int r = f / BT, c = f % BT;
            int kk = k0 + r, t = t_base + c;
            Xs[r][c] = (kk < Cin && t < T) ? Xb[(size_t)kk * T + t] : 0.f;
        }
        // stage W tile [BO][BK]
#pragma unroll
        for (int f = tid; f < BO * BK; f += 256) {
            int r = f / BK, c = f % BK;
            int o = o_base + r, kk = k0 + c;
            Ws[r][c] = (o < Cout && kk < Cin) ? W[(size_t)o * Cin + kk] : 0.f;
        }
        __syncthreads();

#pragma unroll
        for (int k = 0; k < BK; ++k) {
            float4 xv = *(const float4*)&Xs[k][tt * 4];
#pragma unroll
            for (int j = 0; j < OJ; ++j) {
                float w = Ws[to * OJ + j][k];
                acc[j][0] += w * xv.x;
                acc[j][1] += w * xv.y;
                acc[j][2] += w * xv.z;
                acc[j][3] += w * xv.w;
            }
        }
        __syncthreads();
    }

    // epilogue
#pragma unroll
    for (int j = 0; j < OJ; ++j) {
        int o = o_base + to * OJ + j;
        if (o >= Cout) continue;
        float* zrow = Z + ((size_t)b * Cout + o) * T;
#pragma unroll
        for (int u = 0; u < 4; ++u) {
            int t = t_base + tt * 4 + u;
            if (t < T) zrow[t] = acc[j][u];
        }
    }
}

// In-place CUBA-LIF scan over T per (b,c) neuron.
// buf layout [B, C, T]; alpha_c = 0 so current == z_t.
// spiking=1: write heaviside spike; spiking=0: write pre-reset voltage.
__global__ void scan_kernel(float* __restrict__ buf, int BC, int T,
                            float th, int spiking)
{
    int idx = blockIdx.x * blockDim.x + threadIdx.x;
    if (idx >= BC) return;
    float* row = buf + (size_t)idx * T;
    float v = 0.f;
    for (int t = 0; t < T; ++t) {
        float z = row[t];
        v = ALPHA_V * v + z;
        float s = (v >= th) ? 1.f : 0.f;
        row[t] = spiking ? s : v;
        v = v * (1.f - s);   // hard reset to 0 on spike
    }
}

extern "C" void kernel_launch(void* const* d_in, const int* in_sizes, int n_in,
                              void* d_out, int out_size, void* d_ws, size_t ws_size,
                              hipStream_t stream) {
    const float* spike = (const float*)d_in[0];   // [32, 2312, 300]
    const float* W1 = (const float*)d_in[1];      // [64, 2312]
    const float* W2 = (const float*)d_in[2];      // [512, 64]
    const float* W3 = (const float*)d_in[3];      // [512, 512]
    const float* W4 = (const float*)d_in[4];      // [10, 512]
    float* out = (float*)d_out;                   // [32, 10, 300]

    const int B = 32, T = 300, CIN = 34 * 34 * 2; // 2312
    const int H1 = 64, H2 = 512, H3 = 512, H4 = 10;

    // ping-pong workspace: two buffers of max-layer size
    const size_t bufElems = (size_t)B * 512 * T;  // 4.9M floats = 19.7 MB
    float* bufA = (float*)d_ws;
    float* bufB = bufA + bufElems;

    const int tTiles = (T + 63) / 64;  // 5

    // layer 1: Z1 = W1 @ spike   -> bufA
    gemm_bot<64, 64, 16><<<dim3(tTiles, (H1 + 63) / 64, B), 256, 0, stream>>>(
        spike, W1, bufA, B, CIN, H1, T);
    scan_kernel<<<(B * H1 + 255) / 256, 256, 0, stream>>>(bufA, B * H1, T, TH_HID, 1);

    // layer 2: Z2 = W2 @ S1      -> bufB
    gemm_bot<64, 64, 16><<<dim3(tTiles, (H2 + 63) / 64, B), 256, 0, stream>>>(
        bufA, W2, bufB, B, H1, H2, T);
    scan_kernel<<<(B * H2 + 255) / 256, 256, 0, stream>>>(bufB, B * H2, T, TH_HID, 1);

    // layer 3: Z3 = W3 @ S2      -> bufA
    gemm_bot<64, 64, 16><<<dim3(tTiles, (H3 + 63) / 64, B), 256, 0, stream>>>(
        bufB, W3, bufA, B, H2, H3, T);
    scan_kernel<<<(B * H3 + 255) / 256, 256, 0, stream>>>(bufA, B * H3, T, TH_HID, 1);

    // layer 4: Z4 = W4 @ S3      -> d_out, then voltage scan in-place
    gemm_bot<16, 64, 16><<<dim3(tTiles, (H4 + 15) / 16, B), 256, 0, stream>>>(
        bufA, W4, out, B, H3, H4, T);
    scan_kernel<<<(B * H4 + 255) / 256, 256, 0, stream>>>(out, B * H4, T, TH_LAST, 0);
}

// Round 3
// 375.630 us; speedup vs baseline: 2.8272x; 2.8272x over previous
//
#include <hip/hip_runtime.h>

#define ALPHA_V 0.99f
#define TH_HID 0.1f
#define TH_LAST 1.0e5f

static constexpr int B_ = 32, T_ = 300, CIN_ = 2312;

// ---------------------------------------------------------------------------
// Layer-1 GEMM, split-K=4.  X = spike [B][CIN][T] (t contiguous).
// Z[b][t][o] = sum_i W[o][i] * X[b][i][t]   (per K-chunk partial)
// Output P[s][b][t][64].  Tile: 64 t x 64 o, BK=16. grid (5, 4, 32).
// ---------------------------------------------------------------------------
__global__ __launch_bounds__(256) void gemm1_splitk(
    const float* __restrict__ X, const float* __restrict__ W,
    float* __restrict__ P)
{
    const int b = blockIdx.z, s = blockIdx.y;
    const int t0 = blockIdx.x * 64;
    const int ks = s * 578, ke = ks + 578;   // 2312 = 4*578

    __shared__ float As[16][68];   // [k][t]
    __shared__ float Bs[16][68];   // [k][o]

    const int tid = threadIdx.x;
    const int tm = tid >> 4, tn = tid & 15;
    const int m0 = tm * 4, n0 = tn * 4;      // t, o micro-tile bases
    float acc[4][4] = {};

    const float* Xb = X + (size_t)b * CIN_ * T_;
    const int bo = tid >> 2, bq = tid & 3;

    for (int k0 = ks; k0 < ke; k0 += 16) {
        // stage X tile [16 k][64 t] — rows already t-contiguous, coalesced
        float av[4];
#pragma unroll
        for (int j = 0; j < 4; ++j) {
            int e = tid + j * 256;
            int k = e >> 6, t = e & 63;
            int gk = k0 + k, gt = t0 + t;
            av[j] = (gk < ke && gt < T_) ? Xb[(size_t)gk * T_ + gt] : 0.f;
        }
        // stage W tile [64 o][16 k] -> transposed (scalar, guarded at chunk tail)
        float wv[4];
#pragma unroll
        for (int j = 0; j < 4; ++j) {
            int gk = k0 + bq * 4 + j;
            wv[j] = (gk < ke) ? W[(size_t)bo * CIN_ + gk] : 0.f;
        }
        __syncthreads();
#pragma unroll
        for (int j = 0; j < 4; ++j) {
            int e = tid + j * 256;
            As[e >> 6][e & 63] = av[j];
        }
#pragma unroll
        for (int j = 0; j < 4; ++j) Bs[bq * 4 + j][bo] = wv[j];
        __syncthreads();

#pragma unroll
        for (int kk = 0; kk < 16; ++kk) {
            float4 a = *(const float4*)&As[kk][m0];
            float4 w4 = *(const float4*)&Bs[kk][n0];
            acc[0][0] += a.x * w4.x; acc[0][1] += a.x * w4.y; acc[0][2] += a.x * w4.z; acc[0][3] += a.x * w4.w;
            acc[1][0] += a.y * w4.x; acc[1][1] += a.y * w4.y; acc[1][2] += a.y * w4.z; acc[1][3] += a.y * w4.w;
            acc[2][0] += a.z * w4.x; acc[2][1] += a.z * w4.y; acc[2][2] += a.z * w4.z; acc[2][3] += a.z * w4.w;
            acc[3][0] += a.w * w4.x; acc[3][1] += a.w * w4.y; acc[3][2] += a.w * w4.z; acc[3][3] += a.w * w4.w;
        }
    }

    float* Pp = P + ((size_t)s * B_ + b) * T_ * 64;
#pragma unroll
    for (int i = 0; i < 4; ++i) {
        int t = t0 + m0 + i;
        if (t < T_) {
            float4 v = make_float4(acc[i][0], acc[i][1], acc[i][2], acc[i][3]);
            *(float4*)&Pp[(size_t)t * 64 + n0] = v;
        }
    }
}

// ---------------------------------------------------------------------------
// Flat GEMM for layers 2/3:  Z[r][o] = sum_k A[r][k] * W[o][k]
// A: [M][K] row-major (M = B*T = 9600, multiple of 128), W: [N][K].
// Tile 128x64, BK=16, micro 8x4. grid (M/128, N/64).
// ---------------------------------------------------------------------------
__global__ __launch_bounds__(256) void gemm_flat(
    const float* __restrict__ A, const float* __restrict__ W,
    float* __restrict__ Z, int N, int K)
{
    const int r0 = blockIdx.x * 128;
    const int o0 = blockIdx.y * 64;

    __shared__ float As[16][132];  // [k][r]
    __shared__ float Bs[16][68];   // [k][o]

    const int tid = threadIdx.x;
    const int tm = tid >> 4, tn = tid & 15;
    const int m0 = tm * 8, n0 = tn * 4;
    const int ar = tid >> 1, ah = tid & 1;   // A staging: row, k-half
    const int bo = tid >> 2, bq = tid & 3;   // W staging

    float acc[8][4] = {};

    for (int k0 = 0; k0 < K; k0 += 16) {
        const float* Arow = A + (size_t)(r0 + ar) * K + k0 + ah * 8;
        float4 a0 = *(const float4*)(Arow);
        float4 a1 = *(const float4*)(Arow + 4);
        float4 wv = *(const float4*)&W[(size_t)(o0 + bo) * K + k0 + bq * 4];
        __syncthreads();
        {
            int kb = ah * 8;
            As[kb + 0][ar] = a0.x; As[kb + 1][ar] = a0.y; As[kb + 2][ar] = a0.z; As[kb + 3][ar] = a0.w;
            As[kb + 4][ar] = a1.x; As[kb + 5][ar] = a1.y; As[kb + 6][ar] = a1.z; As[kb + 7][ar] = a1.w;
            int kc = bq * 4;
            Bs[kc + 0][bo] = wv.x; Bs[kc + 1][bo] = wv.y; Bs[kc + 2][bo] = wv.z; Bs[kc + 3][bo] = wv.w;
        }
        __syncthreads();

#pragma unroll
        for (int kk = 0; kk < 16; ++kk) {
            float4 x0 = *(const float4*)&As[kk][m0];
            float4 x1 = *(const float4*)&As[kk][m0 + 4];
            float4 y  = *(const float4*)&Bs[kk][n0];
            acc[0][0] += x0.x * y.x; acc[0][1] += x0.x * y.y; acc[0][2] += x0.x * y.z; acc[0][3] += x0.x * y.w;
            acc[1][0] += x0.y * y.x; acc[1][1] += x0.y * y.y; acc[1][2] += x0.y * y.z; acc[1][3] += x0.y * y.w;
            acc[2][0] += x0.z * y.x; acc[2][1] += x0.z * y.y; acc[2][2] += x0.z * y.z; acc[2][3] += x0.z * y.w;
            acc[3][0] += x0.w * y.x; acc[3][1] += x0.w * y.y; acc[3][2] += x0.w * y.z; acc[3][3] += x0.w * y.w;
            acc[4][0] += x1.x * y.x; acc[4][1] += x1.x * y.y; acc[4][2] += x1.x * y.z; acc[4][3] += x1.x * y.w;
            acc[5][0] += x1.y * y.x; acc[5][1] += x1.y * y.y; acc[5][2] += x1.y * y.z; acc[5][3] += x1.y * y.w;
            acc[6][0] += x1.z * y.x; acc[6][1] += x1.z * y.y; acc[6][2] += x1.z * y.z; acc[6][3] += x1.z * y.w;
            acc[7][0] += x1.w * y.x; acc[7][1] += x1.w * y.y; acc[7][2] += x1.w * y.z; acc[7][3] += x1.w * y.w;
        }
    }

#pragma unroll
    for (int i = 0; i < 8; ++i) {
        size_t row = r0 + m0 + i;
        float4 v = make_float4(acc[i][0], acc[i][1], acc[i][2], acc[i][3]);
        *(float4*)&Z[row * N + o0 + n0] = v;
    }
}

// ---------------------------------------------------------------------------
// Fused (optional split-K reduce) + CUBA-LIF scan over T.
// z layout [nsplit][B][T][C]; out [B][T][C].  Block: (c-chunk of <=128, b).
// Stages [64 t][cw] tiles in LDS; scan runs in LDS, conflict-free.
// ---------------------------------------------------------------------------
__global__ __launch_bounds__(256) void scan_fused(
    const float* __restrict__ z, float* __restrict__ out,
    int C, int nsplit, size_t splitStride, float th)
{
    const int b = blockIdx.y;
    const int c0 = blockIdx.x * 128;
    const int cw = min(128, C - c0);
    const int csh = (cw == 128) ? 7 : 6;   // cw is 128 or 64 here

    __shared__ float tile[64][132];
    const int tid = threadIdx.x;
    float v = 0.f;

    for (int tc = 0; tc < T_; tc += 64) {
        const int tl = min(64, T_ - tc);
        const int ne = tl << csh;
        for (int e = tid; e < ne; e += 256) {
            int t = e >> csh, c = e & (cw - 1);
            size_t gi = ((size_t)(b * T_ + tc + t)) * C + c0 + c;
            float val = z[gi];
            for (int s = 1; s < nsplit; ++s) val += z[(size_t)s * splitStride + gi];
            tile[t][c] = val;
        }
        __syncthreads();
        if (tid < cw) {
            const int c = tid;
            for (int t = 0; t < tl; ++t) {
                float vv = ALPHA_V * v + tile[t][c];
                float s = (vv >= th) ? 1.f : 0.f;
                tile[t][c] = s;
                v = vv * (1.f - s);
            }
        }
        __syncthreads();
        for (int e = tid; e < ne; e += 256) {
            int t = e >> csh, c = e & (cw - 1);
            out[((size_t)(b * T_ + tc + t)) * C + c0 + c] = tile[t][c];
        }
        __syncthreads();
    }
}

// ---------------------------------------------------------------------------
// Layer 4: wave per (b,t) row.  S: [9600][512], W4: [10][512] staged in LDS.
// Writes d_out [B][10][T] (scattered 10 stores per wave).
// ---------------------------------------------------------------------------
__global__ __launch_bounds__(256) void gemm4_kernel(
    const float* __restrict__ S, const float* __restrict__ W4,
    float* __restrict__ out)
{
    __shared__ float W4s[10 * 512];
    for (int e = threadIdx.x; e < 10 * 512; e += 256) W4s[e] = W4[e];
    __syncthreads();

    const int wid = (blockIdx.x * 256 + threadIdx.x) >> 6;
    const int l = threadIdx.x & 63;
    if (wid >= B_ * T_) return;
    const int b = wid / T_, t = wid % T_;

    const float* Srow = S + (size_t)wid * 512;
    float acc[10] = {};
#pragma unroll
    for (int j = 0; j < 8; ++j) {
        float sv = Srow[j * 64 + l];
#pragma unroll
        for (int o = 0; o < 10; ++o)
            acc[o] += sv * W4s[o * 512 + j * 64 + l];
    }
#pragma unroll
    for (int o = 0; o < 10; ++o) {
        float v = acc[o];
        v += __shfl_xor(v, 32); v += __shfl_xor(v, 16); v += __shfl_xor(v, 8);
        v += __shfl_xor(v, 4);  v += __shfl_xor(v, 2);  v += __shfl_xor(v, 1);
        if (l == 0) out[((size_t)b * 10 + o) * T_ + t] = v;
    }
}

// ---------------------------------------------------------------------------
// Readout scan (voltage, never resets in practice). In-place on [B][10][T].
// Block per b; stage [10][300] in LDS.
// ---------------------------------------------------------------------------
__global__ __launch_bounds__(256) void scan4_kernel(float* __restrict__ out)
{
    const int b = blockIdx.x;
    __shared__ float tile[10][304];
    float* base = out + (size_t)b * 10 * T_;
    for (int e = threadIdx.x; e < 10 * T_; e += 256) tile[e / T_][e % T_] = base[e];
    __syncthreads();
    if (threadIdx.x < 10) {
        const int o = threadIdx.x;
        float v = 0.f;
        for (int t = 0; t < T_; ++t) {
            v = ALPHA_V * v + tile[o][t];
            float s = (v >= TH_LAST) ? 1.f : 0.f;
            tile[o][t] = v;           // pre-reset voltage is the output
            v *= (1.f - s);
        }
    }
    __syncthreads();
    for (int e = threadIdx.x; e < 10 * T_; e += 256) base[e] = tile[e / T_][e % T_];
}

extern "C" void kernel_launch(void* const* d_in, const int* in_sizes, int n_in,
                              void* d_out, int out_size, void* d_ws, size_t ws_size,
                              hipStream_t stream) {
    const float* spike = (const float*)d_in[0];   // [32, 2312, 300]
    const float* W1 = (const float*)d_in[1];      // [64, 2312]
    const float* W2 = (const float*)d_in[2];      // [512, 64]
    const float* W3 = (const float*)d_in[3];      // [512, 512]
    const float* W4 = (const float*)d_in[4];      // [10, 512]
    float* out = (float*)d_out;                   // [32, 10, 300]

    // Workspace: two 19.66 MB regions (same footprint as round 1).
    // A: S1 [B,T,64] then Z3/S3 [B,T,512].   B: P [4][B,T,64] then Z2/S2.
    const size_t regionElems = (size_t)B_ * T_ * 512;   // 4,915,200 floats
    float* bufA = (float*)d_ws;
    float* bufB = bufA + regionElems;

    // layer 1: split-K GEMM -> partials in bufB; scan1 fuses the reduction
    gemm1_splitk<<<dim3(5, 4, 32), 256, 0, stream>>>(spike, W1, bufB);
    scan_fused<<<dim3(1, 32), 256, 0, stream>>>(
        bufB, bufA, 64, 4, (size_t)B_ * T_ * 64, TH_HID);

    // layer 2: [9600x64]@[64x512] -> bufB (overwrites dead partials)
    gemm_flat<<<dim3(75, 8), 256, 0, stream>>>(bufA, W2, bufB, 512, 64);
    scan_fused<<<dim3(4, 32), 256, 0, stream>>>(bufB, bufB, 512, 1, 0, TH_HID);

    // layer 3: [9600x512]@[512x512] -> bufA (S1 is dead)
    gemm_flat<<<dim3(75, 8), 256, 0, stream>>>(bufB, W3, bufA, 512, 512);
    scan_fused<<<dim3(4, 32), 256, 0, stream>>>(bufA, bufA, 512, 1, 0, TH_HID);

    // layer 4: wave-per-row -> d_out [B,10,T]; voltage scan in-place
    gemm4_kernel<<<2400, 256, 0, stream>>>(bufA, W4, out);
    scan4_kernel<<<32, 256, 0, stream>>>(out);
}

// Round 5
// 373.804 us; speedup vs baseline: 2.8410x; 1.0049x over previous
//
#include <hip/hip_runtime.h>
#include <hip/hip_bf16.h>

#define ALPHA_V 0.99f
#define TH_HID 0.1f
#define TH_LAST 1.0e5f

static constexpr int B_ = 32, T_ = 300, CIN_ = 2312;
static constexpr int KP1 = 2336;          // CIN padded to 73*32
static constexpr int M_ = 9600;           // B*T

using short8 = __attribute__((ext_vector_type(8))) short;
using f32x4  = __attribute__((ext_vector_type(4))) float;

__device__ __forceinline__ float bf16bits_to_f(ushort u) {
    union { unsigned int i; float f; } cv; cv.i = ((unsigned int)u) << 16; return cv.f;
}

// ---------------------------------------------------------------------------
// Transpose + bf16 convert: X [B][CIN][T] f32 -> Xt [B*T][KP1] bf16 (zero-pad K)
// ---------------------------------------------------------------------------
__global__ __launch_bounds__(256) void transpose_x(
    const float* __restrict__ X, ushort* __restrict__ Xt)
{
    __shared__ float tile[64][65];
    const int i0 = blockIdx.x * 64, t0 = blockIdx.y * 64, b = blockIdx.z;
    const int tid = threadIdx.x;
    for (int e = tid; e < 4096; e += 256) {
        int il = e >> 6, tl = e & 63;
        int gi = i0 + il, gt = t0 + tl;
        float v = 0.f;
        if (gi < CIN_ && gt < T_) v = X[((size_t)b * CIN_ + gi) * T_ + gt];
        tile[il][tl] = v;
    }
    __syncthreads();
    for (int e = tid; e < 4096; e += 256) {
        int tl = e >> 6, il = e & 63;
        int gi = i0 + il, gt = t0 + tl;
        if (gi < KP1 && gt < T_) {
            __hip_bfloat16 h = __float2bfloat16(tile[il][tl]);
            Xt[((size_t)b * T_ + gt) * KP1 + gi] = *(ushort*)&h;
        }
    }
}

// ---------------------------------------------------------------------------
// Weight split: W f32 [N][K] -> Whi/Wlo bf16 [N][Kp], W == hi + lo (+4e-6 rel)
// ---------------------------------------------------------------------------
__global__ void prep_w(const float* __restrict__ W, ushort* __restrict__ Whi,
                       ushort* __restrict__ Wlo, int N, int K, int Kp)
{
    int idx = blockIdx.x * 256 + threadIdx.x;
    if (idx >= N * Kp) return;
    int n = idx / Kp, k = idx % Kp;
    float w = (k < K) ? W[(size_t)n * K + k] : 0.f;
    __hip_bfloat16 hi = __float2bfloat16(w);
    float hif = __bfloat162float(hi);
    __hip_bfloat16 lo = __float2bfloat16(w - hif);
    Whi[idx] = *(ushort*)&hi;
    Wlo[idx] = *(ushort*)&lo;
}

// ---------------------------------------------------------------------------
// MFMA GEMM:  Z[m][n] = sum_k A[m][k] * (Whi[n][k] + Wlo[n][k])
// A bf16 [M][lda], Whi/Wlo bf16 [N][lda].  BM=128, BN in {128,64}, BK=32.
// 4 waves as 2x2 (wave tile 64 x BN/2).  mfma_f32_16x16x32_bf16, fp32 acc.
// grid (M/128, N/BN, nsplit); split z covers kChunkSteps K-steps.
// ---------------------------------------------------------------------------
template<int BN, int FN>
__global__ __launch_bounds__(256) void gemm_mfma(
    const ushort* __restrict__ A, const ushort* __restrict__ Whi,
    const ushort* __restrict__ Wlo, float* __restrict__ Zb,
    int lda, int ldz, int kChunkSteps, int kTotalSteps, size_t zSplitStride)
{
    constexpr int FM = 4;
    constexpr int LP = 40;                 // LDS row pitch (bf16) = 32 + 8 pad
    __shared__ ushort As[128 * LP];
    __shared__ ushort Bh[BN * LP];
    __shared__ ushort Bl[BN * LP];

    const int tid = threadIdx.x;
    const int m0 = blockIdx.x * 128;
    const int n0 = blockIdx.y * BN;
    const int stepBeg = blockIdx.z * kChunkSteps;
    const int nSteps = min(kChunkSteps, kTotalSteps - stepBeg);
    float* Z = Zb + (size_t)blockIdx.z * zSplitStride;

    const int wid = tid >> 6, lane = tid & 63;
    const int wm = (wid >> 1) * 64;
    const int wn = (wid & 1) * (BN / 2);
    const int lr = lane & 15, lk = (lane >> 4) * 8;

    f32x4 acc[FM][FN];
    {
        f32x4 zero = {0.f, 0.f, 0.f, 0.f};
        for (int i = 0; i < FM; ++i)
            for (int j = 0; j < FN; ++j) acc[i][j] = zero;
    }

    // staging assignments
    const int ar = tid >> 1, aq = tid & 1;         // A: 2 thr/row, 32B each
    const ushort* Arow = A + (size_t)(m0 + ar) * lda + (size_t)stepBeg * 32 + aq * 16;
    const ushort* Hrow; const ushort* Lrow;
    if constexpr (BN == 128) {
        Hrow = Whi + (size_t)(n0 + (tid >> 1)) * lda + (size_t)stepBeg * 32 + (tid & 1) * 16;
        Lrow = Wlo + (size_t)(n0 + (tid >> 1)) * lda + (size_t)stepBeg * 32 + (tid & 1) * 16;
    } else {
        Hrow = Whi + (size_t)(n0 + (tid >> 2)) * lda + (size_t)stepBeg * 32 + (tid & 3) * 8;
        Lrow = Wlo + (size_t)(n0 + (tid >> 2)) * lda + (size_t)stepBeg * 32 + (tid & 3) * 8;
    }

    uint4 ra[2], rh[2], rl[2];
    auto loadstep = [&](int s) {
        const ushort* ap = Arow + s * 32;
        ra[0] = *(const uint4*)(ap);
        ra[1] = *(const uint4*)(ap + 8);
        if constexpr (BN == 128) {
            const ushort* hp = Hrow + s * 32;
            const ushort* lp = Lrow + s * 32;
            rh[0] = *(const uint4*)(hp); rh[1] = *(const uint4*)(hp + 8);
            rl[0] = *(const uint4*)(lp); rl[1] = *(const uint4*)(lp + 8);
        } else {
            rh[0] = *(const uint4*)(Hrow + s * 32);
            rl[0] = *(const uint4*)(Lrow + s * 32);
        }
    };

    loadstep(0);
    for (int s = 0; s < nSteps; ++s) {
        // LDS writes of current step
        *(uint4*)&As[ar * LP + aq * 16]     = ra[0];
        *(uint4*)&As[ar * LP + aq * 16 + 8] = ra[1];
        if constexpr (BN == 128) {
            int br = tid >> 1, bq = (tid & 1) * 16;
            *(uint4*)&Bh[br * LP + bq]     = rh[0];
            *(uint4*)&Bh[br * LP + bq + 8] = rh[1];
            *(uint4*)&Bl[br * LP + bq]     = rl[0];
            *(uint4*)&Bl[br * LP + bq + 8] = rl[1];
        } else {
            int br = tid >> 2, bq = (tid & 3) * 8;
            *(uint4*)&Bh[br * LP + bq] = rh[0];
            *(uint4*)&Bl[br * LP + bq] = rl[0];
        }
        __syncthreads();
        if (s + 1 < nSteps) loadstep(s + 1);   // prefetch overlaps MFMAs below

        short8 af[FM], bhf[FN], blf[FN];
#pragma unroll
        for (int fm = 0; fm < FM; ++fm)
            af[fm] = *(const short8*)&As[(wm + fm * 16 + lr) * LP + lk];
#pragma unroll
        for (int fn = 0; fn < FN; ++fn) {
            bhf[fn] = *(const short8*)&Bh[(wn + fn * 16 + lr) * LP + lk];
            blf[fn] = *(const short8*)&Bl[(wn + fn * 16 + lr) * LP + lk];
        }
#pragma unroll
        for (int fm = 0; fm < FM; ++fm)
#pragma unroll
            for (int fn = 0; fn < FN; ++fn) {
                acc[fm][fn] = __builtin_amdgcn_mfma_f32_16x16x32_bf16(af[fm], bhf[fn], acc[fm][fn], 0, 0, 0);
                acc[fm][fn] = __builtin_amdgcn_mfma_f32_16x16x32_bf16(af[fm], blf[fn], acc[fm][fn], 0, 0, 0);
            }
        __syncthreads();
    }

    // epilogue: C/D layout col = lane&15, row = (lane>>4)*4 + r   [m89-verified]
    const int orow = (lane >> 4) * 4;
#pragma unroll
    for (int fm = 0; fm < FM; ++fm)
#pragma unroll
        for (int fn = 0; fn < FN; ++fn)
#pragma unroll
            for (int r = 0; r < 4; ++r)
                Z[(size_t)(m0 + wm + fm * 16 + orow + r) * ldz + (n0 + wn + fn * 16 + lr)]
                    = acc[fm][fn][r];
}

// ---------------------------------------------------------------------------
// (optional split-K reduce) + CUBA-LIF scan over T; emits bf16 spikes.
// z: [nsplit][B][T][C] f32, out: [B][T][C] bf16.
// ---------------------------------------------------------------------------
__global__ __launch_bounds__(256) void scan_fused(
    const float* __restrict__ z, __hip_bfloat16* __restrict__ out,
    int C, int nsplit, size_t splitStride, float th)
{
    const int b = blockIdx.y;
    const int c0 = blockIdx.x * 128;
    const int cw = min(128, C - c0);
    const int csh = (cw == 128) ? 7 : 6;

    __shared__ float tile[64][132];
    const int tid = threadIdx.x;
    float v = 0.f;

    for (int tc = 0; tc < T_; tc += 64) {
        const int tl = min(64, T_ - tc);
        const int ne = tl << csh;
        for (int e = tid; e < ne; e += 256) {
            int t = e >> csh, c = e & (cw - 1);
            size_t gi = ((size_t)(b * T_ + tc + t)) * C + c0 + c;
            float val = z[gi];
            for (int s = 1; s < nsplit; ++s) val += z[(size_t)s * splitStride + gi];
            tile[t][c] = val;
        }
        __syncthreads();
        if (tid < cw) {
            const int c = tid;
            for (int t = 0; t < tl; ++t) {
                float vv = ALPHA_V * v + tile[t][c];
                float s = (vv >= th) ? 1.f : 0.f;
                tile[t][c] = s;
                v = vv * (1.f - s);
            }
        }
        __syncthreads();
        for (int e = tid; e < ne; e += 256) {
            int t = e >> csh, c = e & (cw - 1);
            out[((size_t)(b * T_ + tc + t)) * C + c0 + c] = __float2bfloat16(tile[t][c]);
        }
        __syncthreads();
    }
}

// ---------------------------------------------------------------------------
// Layer 4: wave per (b,t) row. S bf16 [9600][512], W4 f32 [10][512] in LDS.
// ---------------------------------------------------------------------------
__global__ __launch_bounds__(256) void gemm4_kernel(
    const ushort* __restrict__ S, const float* __restrict__ W4,
    float* __restrict__ out)
{
    __shared__ float W4s[10 * 512];
    for (int e = threadIdx.x; e < 5120; e += 256) W4s[e] = W4[e];
    __syncthreads();

    const int wid = (blockIdx.x * 256 + threadIdx.x) >> 6;
    const int l = threadIdx.x & 63;
    const int b = wid / T_, t = wid % T_;

    const ushort* Srow = S + (size_t)wid * 512;
    float acc[10] = {};
#pragma unroll
    for (int j = 0; j < 2; ++j) {
        ushort4 sv = *(const ushort4*)&Srow[j * 256 + l * 4];
        float s0 = bf16bits_to_f(sv.x), s1 = bf16bits_to_f(sv.y),
              s2 = bf16bits_to_f(sv.z), s3 = bf16bits_to_f(sv.w);
#pragma unroll
        for (int o = 0; o < 10; ++o) {
            float4 wv = *(const float4*)&W4s[o * 512 + j * 256 + l * 4];
            acc[o] += s0 * wv.x + s1 * wv.y + s2 * wv.z + s3 * wv.w;
        }
    }
#pragma unroll
    for (int o = 0; o < 10; ++o) {
        float v = acc[o];
        v += __shfl_xor(v, 32); v += __shfl_xor(v, 16); v += __shfl_xor(v, 8);
        v += __shfl_xor(v, 4);  v += __shfl_xor(v, 2);  v += __shfl_xor(v, 1);
        if (l == 0) out[((size_t)b * 10 + o) * T_ + t] = v;
    }
}

// ---------------------------------------------------------------------------
// Readout voltage scan, in-place on [B][10][T].
// ---------------------------------------------------------------------------
__global__ __launch_bounds__(256) void scan4_kernel(float* __restrict__ out)
{
    const int b = blockIdx.x;
    __shared__ float tile[10][304];
    float* base = out + (size_t)b * 10 * T_;
    for (int e = threadIdx.x; e < 10 * T_; e += 256) tile[e / T_][e % T_] = base[e];
    __syncthreads();
    if (threadIdx.x < 10) {
        const int o = threadIdx.x;
        float v = 0.f;
        for (int t = 0; t < T_; ++t) {
            v = ALPHA_V * v + tile[o][t];
            float s = (v >= TH_LAST) ? 1.f : 0.f;
            tile[o][t] = v;
            v *= (1.f - s);
        }
    }
    __syncthreads();
    for (int e = threadIdx.x; e < 10 * T_; e += 256) base[e] = tile[e / T_][e % T_];
}

extern "C" void kernel_launch(void* const* d_in, const int* in_sizes, int n_in,
                              void* d_out, int out_size, void* d_ws, size_t ws_size,
                              hipStream_t stream) {
    const float* spike = (const float*)d_in[0];   // [32, 2312, 300]
    const float* W1 = (const float*)d_in[1];      // [64, 2312]
    const float* W2 = (const float*)d_in[2];      // [512, 64]
    const float* W3 = (const float*)d_in[3];      // [512, 512]
    const float* W4 = (const float*)d_in[4];      // [10, 512]
    float* out = (float*)d_out;                   // [32, 10, 300]

    // ---- workspace layout (58 MB; Xt region reused for Z/S2/S3 after gemm1)
    char* ws = (char*)d_ws;
    ushort* Xt = (ushort*)ws;                               // [9600][2336] bf16 = 44,851,200 B
    float*  Zf = (float*)ws;                                // [9600][512] f32 (reuse, gemm1 done)
    __hip_bfloat16* S2 = (__hip_bfloat16*)(ws + 20971520);  // [9600][512] bf16
    __hip_bfloat16* S3 = (__hip_bfloat16*)(ws + 31457280);  // [9600][512] bf16
    float* P  = (float*)(ws + 44851200);                    // [4][9600][64] f32 partials
    __hip_bfloat16* S1 = (__hip_bfloat16*)(ws + 54681600);  // [9600][64] bf16
    ushort* W1hi = (ushort*)(ws + 55910400);
    ushort* W1lo = W1hi + (size_t)64 * KP1;
    ushort* W2hi = W1lo + (size_t)64 * KP1;
    ushort* W2lo = W2hi + (size_t)512 * 64;
    ushort* W3hi = W2lo + (size_t)512 * 64;
    ushort* W3lo = W3hi + (size_t)512 * 512;                // end ~57.7 MB

    // ---- prep: transpose spikes to bf16 [M][K], split weights hi/lo
    transpose_x<<<dim3(37, 5, 32), 256, 0, stream>>>(spike, Xt);
    prep_w<<<(64 * KP1 + 255) / 256, 256, 0, stream>>>(W1, W1hi, W1lo, 64, CIN_, KP1);
    prep_w<<<(512 * 64 + 255) / 256, 256, 0, stream>>>(W2, W2hi, W2lo, 512, 64, 64);
    prep_w<<<(512 * 512 + 255) / 256, 256, 0, stream>>>(W3, W3hi, W3lo, 512, 512, 512);

    // ---- layer 1: MFMA split-K=4 (73 K-steps -> 19/19/19/16), scan1 reduces
    gemm_mfma<64, 2><<<dim3(75, 1, 4), 256, 0, stream>>>(
        Xt, W1hi, W1lo, P, KP1, 64, 19, 73, (size_t)M_ * 64);
    scan_fused<<<dim3(1, 32), 256, 0, stream>>>(P, S1, 64, 4, (size_t)M_ * 64, TH_HID);

    // ---- layer 2
    gemm_mfma<128, 4><<<dim3(75, 4, 1), 256, 0, stream>>>(
        (const ushort*)S1, W2hi, W2lo, Zf, 64, 512, 2, 2, 0);
    scan_fused<<<dim3(4, 32), 256, 0, stream>>>(Zf, S2, 512, 1, 0, TH_HID);

    // ---- layer 3
    gemm_mfma<128, 4><<<dim3(75, 4, 1), 256, 0, stream>>>(
        (const ushort*)S2, W3hi, W3lo, Zf, 512, 512, 16, 16, 0);
    scan_fused<<<dim3(4, 32), 256, 0, stream>>>(Zf, S3, 512, 1, 0, TH_HID);

    // ---- layer 4 + readout scan
    gemm4_kernel<<<2400, 256, 0, stream>>>((const ushort*)S3, W4, out);
    scan4_kernel<<<32, 256, 0, stream>>>(out);
}

// Round 6
// 210.103 us; speedup vs baseline: 5.0546x; 1.7791x over previous
//
#include <hip/hip_runtime.h>
#include <hip/hip_bf16.h>

#define ALPHA_V 0.99f
#define TH_HID 0.1f
#define TH_LAST 1.0e5f

static constexpr int B_ = 32, T_ = 300, CIN_ = 2312;
static constexpr int KP1 = 2336;          // CIN padded to 73*32
static constexpr int M_ = 9600;           // B*T

using short8 = __attribute__((ext_vector_type(8))) short;
using f32x4  = __attribute__((ext_vector_type(4))) float;

__device__ __forceinline__ float bf16bits_to_f(ushort u) {
    union { unsigned int i; float f; } cv; cv.i = ((unsigned int)u) << 16; return cv.f;
}

// ---------------------------------------------------------------------------
// Transpose + bf16 convert: X [B][CIN][T] f32 -> Xt [B*T][KP1] bf16 (zero-pad)
// float4 loads, ushort8 (16B) stores.
// ---------------------------------------------------------------------------
__global__ __launch_bounds__(256) void transpose_x(
    const float* __restrict__ X, ushort* __restrict__ Xt)
{
    __shared__ float tile[64][65];
    const int i0 = blockIdx.x * 64, t0 = blockIdx.y * 64, b = blockIdx.z;
    const int tid = threadIdx.x;

    if (t0 + 64 <= T_) {
        // full t-tile: vectorized loads (row base is 16B aligned: 300*gi + t0 ≡ 0 mod 4)
#pragma unroll
        for (int j = 0; j < 4; ++j) {
            int e = tid + j * 256;          // 1024 items: [il][tq]
            int il = e >> 4, tq = e & 15;
            int gi = i0 + il;
            float4 v = make_float4(0.f, 0.f, 0.f, 0.f);
            if (gi < CIN_) v = *(const float4*)&X[((size_t)b * CIN_ + gi) * T_ + t0 + tq * 4];
            tile[il][tq * 4 + 0] = v.x; tile[il][tq * 4 + 1] = v.y;
            tile[il][tq * 4 + 2] = v.z; tile[il][tq * 4 + 3] = v.w;
        }
    } else {
        for (int e = tid; e < 4096; e += 256) {
            int il = e >> 6, tl = e & 63;
            int gi = i0 + il, gt = t0 + tl;
            float v = 0.f;
            if (gi < CIN_ && gt < T_) v = X[((size_t)b * CIN_ + gi) * T_ + gt];
            tile[il][tl] = v;
        }
    }
    __syncthreads();
#pragma unroll
    for (int j = 0; j < 2; ++j) {
        int e = tid + j * 256;              // 512 items: [tl][ig]
        int tl = e >> 3, ig = e & 7;
        int gt = t0 + tl, gi0 = i0 + ig * 8;
        if (gt < T_ && gi0 < KP1) {
            ushort w[8];
#pragma unroll
            for (int k = 0; k < 8; ++k) {
                __hip_bfloat16 h = __float2bfloat16(tile[ig * 8 + k][tl]);
                w[k] = *(ushort*)&h;
            }
            *(uint4*)&Xt[((size_t)b * T_ + gt) * KP1 + gi0] = *(uint4*)w;
        }
    }
}

// ---------------------------------------------------------------------------
// Weight split: W f32 [N][K] -> Whi/Wlo bf16 [N][Kp], W == hi + lo
// ---------------------------------------------------------------------------
__global__ void prep_w(const float* __restrict__ W, ushort* __restrict__ Whi,
                       ushort* __restrict__ Wlo, int N, int K, int Kp)
{
    int idx = blockIdx.x * 256 + threadIdx.x;
    if (idx >= N * Kp) return;
    int n = idx / Kp, k = idx % Kp;
    float w = (k < K) ? W[(size_t)n * K + k] : 0.f;
    __hip_bfloat16 hi = __float2bfloat16(w);
    float hif = __bfloat162float(hi);
    __hip_bfloat16 lo = __float2bfloat16(w - hif);
    Whi[idx] = *(ushort*)&hi;
    Wlo[idx] = *(ushort*)&lo;
}

// ---------------------------------------------------------------------------
// MFMA GEMM 64x64 tile, BK=32, double-buffered LDS, one barrier per K-step.
// Z[m][n] = sum_k A[m][k]*(Whi[n][k]+Wlo[n][k]).  4 waves as 2x2 (32x32 each),
// FM=FN=2, mfma_f32_16x16x32_bf16.  grid (M/64, N/64, nsplit).
// ---------------------------------------------------------------------------
__global__ __launch_bounds__(256) void gemm_mfma64(
    const ushort* __restrict__ A, const ushort* __restrict__ Whi,
    const ushort* __restrict__ Wlo, float* __restrict__ Zb,
    int lda, int ldz, int kChunkSteps, int kTotalSteps, size_t zSplitStride)
{
    constexpr int LP = 40;                 // LDS pitch (elems): 32 + 8 pad
    __shared__ ushort As[2][64 * LP];
    __shared__ ushort Bh[2][64 * LP];
    __shared__ ushort Bl[2][64 * LP];

    const int tid = threadIdx.x;
    const int m0 = blockIdx.x * 64, n0 = blockIdx.y * 64;
    const int stepBeg = blockIdx.z * kChunkSteps;
    const int nSteps = min(kChunkSteps, kTotalSteps - stepBeg);
    float* Z = Zb + (size_t)blockIdx.z * zSplitStride;

    const int wid = tid >> 6, lane = tid & 63;
    const int wm = (wid >> 1) * 32, wn = (wid & 1) * 32;
    const int lr = lane & 15, lk = (lane >> 4) * 8;

    f32x4 acc[2][2];
    {
        f32x4 z4 = {0.f, 0.f, 0.f, 0.f};
        acc[0][0] = z4; acc[0][1] = z4; acc[1][0] = z4; acc[1][1] = z4;
    }

    // staging: 256 threads cover 64 rows x 32 elems (16B each)
    const int sr = tid >> 2;
    const int sq = (tid & 3) * 8;
    const ushort* Ap = A   + (size_t)(m0 + sr) * lda + (size_t)stepBeg * 32 + sq;
    const ushort* Hp = Whi + (size_t)(n0 + sr) * lda + (size_t)stepBeg * 32 + sq;
    const ushort* Lp = Wlo + (size_t)(n0 + sr) * lda + (size_t)stepBeg * 32 + sq;
    const int sdst = sr * LP + sq;

    uint4 ra = *(const uint4*)(Ap);
    uint4 rh = *(const uint4*)(Hp);
    uint4 rl = *(const uint4*)(Lp);
    *(uint4*)&As[0][sdst] = ra;
    *(uint4*)&Bh[0][sdst] = rh;
    *(uint4*)&Bl[0][sdst] = rl;

    for (int s = 0; s < nSteps; ++s) {
        const int cur = s & 1, nxt = cur ^ 1;
        if (s + 1 < nSteps) {               // issue next-step loads early
            ra = *(const uint4*)(Ap + (size_t)(s + 1) * 32);
            rh = *(const uint4*)(Hp + (size_t)(s + 1) * 32);
            rl = *(const uint4*)(Lp + (size_t)(s + 1) * 32);
        }
        __syncthreads();                    // buf[cur] writes visible

        short8 af[2], bhf[2], blf[2];
#pragma unroll
        for (int i = 0; i < 2; ++i) {
            af[i]  = *(const short8*)&As[cur][(wm + i * 16 + lr) * LP + lk];
            bhf[i] = *(const short8*)&Bh[cur][(wn + i * 16 + lr) * LP + lk];
            blf[i] = *(const short8*)&Bl[cur][(wn + i * 16 + lr) * LP + lk];
        }
#pragma unroll
        for (int i = 0; i < 2; ++i)
#pragma unroll
            for (int j = 0; j < 2; ++j) {
                acc[i][j] = __builtin_amdgcn_mfma_f32_16x16x32_bf16(af[i], bhf[j], acc[i][j], 0, 0, 0);
                acc[i][j] = __builtin_amdgcn_mfma_f32_16x16x32_bf16(af[i], blf[j], acc[i][j], 0, 0, 0);
            }
        if (s + 1 < nSteps) {               // write other buffer (no barrier needed)
            *(uint4*)&As[nxt][sdst] = ra;
            *(uint4*)&Bh[nxt][sdst] = rh;
            *(uint4*)&Bl[nxt][sdst] = rl;
        }
    }

    // C/D layout: col = lane&15, row = (lane>>4)*4 + r
    const int orow = (lane >> 4) * 4;
#pragma unroll
    for (int i = 0; i < 2; ++i)
#pragma unroll
        for (int j = 0; j < 2; ++j)
#pragma unroll
            for (int r = 0; r < 4; ++r)
                Z[(size_t)(m0 + wm + i * 16 + orow + r) * ldz + (n0 + wn + j * 16 + lr)]
                    = acc[i][j][r];
}

// ---------------------------------------------------------------------------
// Split-K partial reduction: P [nsplit][n*4 floats] -> Z [n*4], float4-wide.
// ---------------------------------------------------------------------------
__global__ __launch_bounds__(256) void reduce4(
    const float4* __restrict__ P, float4* __restrict__ Z,
    int n, int nsplit, size_t strideF4)
{
    int idx = blockIdx.x * 256 + threadIdx.x;
    if (idx >= n) return;
    float4 a = P[idx];
    for (int s = 1; s < nsplit; ++s) {
        float4 b = P[(size_t)s * strideF4 + idx];
        a.x += b.x; a.y += b.y; a.z += b.z; a.w += b.w;
    }
    Z[idx] = a;
}

// ---------------------------------------------------------------------------
// CUBA-LIF scan, thread per (b,c) neuron.  z f32 [B][T][C] -> spikes bf16.
// Loads are independent of the v-chain -> compiler pipelines them.
// ---------------------------------------------------------------------------
__global__ __launch_bounds__(256) void scan_tpn(
    const float* __restrict__ z, ushort* __restrict__ out,
    int shiftC, float th)
{
    const int C = 1 << shiftC;
    int idx = blockIdx.x * 256 + threadIdx.x;
    if (idx >= B_ * C) return;
    const int b = idx >> shiftC, c = idx & (C - 1);
    const float* zp = z + (size_t)b * T_ * C + c;
    ushort* op = out + (size_t)b * T_ * C + c;
    float v = 0.f;
#pragma unroll 4
    for (int t = 0; t < T_; ++t) {
        float zv = zp[(size_t)t * C];
        v = ALPHA_V * v + zv;
        bool sp = (v >= th);
        op[(size_t)t * C] = sp ? (ushort)0x3F80 : (ushort)0;   // bf16 1.0 / 0.0
        v = sp ? 0.f : v;
    }
}

// ---------------------------------------------------------------------------
// Layer 4: wave per (b,t) row. S bf16 [9600][512], W4 f32 [10][512] in LDS.
// ---------------------------------------------------------------------------
__global__ __launch_bounds__(256) void gemm4_kernel(
    const ushort* __restrict__ S, const float* __restrict__ W4,
    float* __restrict__ out)
{
    __shared__ float W4s[10 * 512];
    for (int e = threadIdx.x; e < 5120; e += 256) W4s[e] = W4[e];
    __syncthreads();

    const int wid = (blockIdx.x * 256 + threadIdx.x) >> 6;
    const int l = threadIdx.x & 63;
    const int b = wid / T_, t = wid % T_;

    const ushort* Srow = S + (size_t)wid * 512;
    float acc[10] = {};
#pragma unroll
    for (int j = 0; j < 2; ++j) {
        ushort4 sv = *(const ushort4*)&Srow[j * 256 + l * 4];
        float s0 = bf16bits_to_f(sv.x), s1 = bf16bits_to_f(sv.y),
              s2 = bf16bits_to_f(sv.z), s3 = bf16bits_to_f(sv.w);
#pragma unroll
        for (int o = 0; o < 10; ++o) {
            float4 wv = *(const float4*)&W4s[o * 512 + j * 256 + l * 4];
            acc[o] += s0 * wv.x + s1 * wv.y + s2 * wv.z + s3 * wv.w;
        }
    }
#pragma unroll
    for (int o = 0; o < 10; ++o) {
        float v = acc[o];
        v += __shfl_xor(v, 32); v += __shfl_xor(v, 16); v += __shfl_xor(v, 8);
        v += __shfl_xor(v, 4);  v += __shfl_xor(v, 2);  v += __shfl_xor(v, 1);
        if (l == 0) out[((size_t)b * 10 + o) * T_ + t] = v;
    }
}

// ---------------------------------------------------------------------------
// Readout voltage scan: thread per (b,o), contiguous T row, in-place.
// ---------------------------------------------------------------------------
__global__ void scan4_tpn(float* __restrict__ out)
{
    int idx = blockIdx.x * 64 + threadIdx.x;
    if (idx >= B_ * 10) return;
    float* p = out + (size_t)idx * T_;
    float v = 0.f;
#pragma unroll 4
    for (int t = 0; t < T_; ++t) {
        v = ALPHA_V * v + p[t];
        p[t] = v;                          // pre-reset voltage is the output
        if (v >= TH_LAST) v = 0.f;
    }
}

extern "C" void kernel_launch(void* const* d_in, const int* in_sizes, int n_in,
                              void* d_out, int out_size, void* d_ws, size_t ws_size,
                              hipStream_t stream) {
    const float* spike = (const float*)d_in[0];   // [32, 2312, 300]
    const float* W1 = (const float*)d_in[1];      // [64, 2312]
    const float* W2 = (const float*)d_in[2];      // [512, 64]
    const float* W3 = (const float*)d_in[3];      // [512, 512]
    const float* W4 = (const float*)d_in[4];      // [10, 512]
    float* out = (float*)d_out;                   // [32, 10, 300]

    // ---- workspace layout (~57.7 MB)
    char* ws = (char*)d_ws;
    ushort* Xt = (ushort*)ws;                               // [9600][2336] bf16 (dead after gemm1)
    float*  Z1 = (float*)ws;                                // [9600][64] f32 (reuse after gemm1)
    float*  Zf = (float*)ws;                                // [9600][512] f32 (reuse after scan1)
    ushort* S2 = (ushort*)(ws + 20971520);                  // [9600][512] bf16
    ushort* S3 = (ushort*)(ws + 31457280);                  // [9600][512] bf16
    float*  P  = (float*)(ws + 44851200);                   // [4][9600][64] f32 partials
    ushort* S1 = (ushort*)(ws + 54681600);                  // [9600][64] bf16
    ushort* W1hi = (ushort*)(ws + 55910400);
    ushort* W1lo = W1hi + (size_t)64 * KP1;
    ushort* W2hi = W1lo + (size_t)64 * KP1;
    ushort* W2lo = W2hi + (size_t)512 * 64;
    ushort* W3hi = W2lo + (size_t)512 * 64;
    ushort* W3lo = W3hi + (size_t)512 * 512;

    // ---- prep
    transpose_x<<<dim3(37, 5, 32), 256, 0, stream>>>(spike, Xt);
    prep_w<<<(64 * KP1 + 255) / 256, 256, 0, stream>>>(W1, W1hi, W1lo, 64, CIN_, KP1);
    prep_w<<<(512 * 64 + 255) / 256, 256, 0, stream>>>(W2, W2hi, W2lo, 512, 64, 64);
    prep_w<<<(512 * 512 + 255) / 256, 256, 0, stream>>>(W3, W3hi, W3lo, 512, 512, 512);

    // ---- layer 1: split-K=4 (73 steps -> 19/19/19/16), reduce, scan
    gemm_mfma64<<<dim3(150, 1, 4), 256, 0, stream>>>(
        Xt, W1hi, W1lo, P, KP1, 64, 19, 73, (size_t)M_ * 64);
    reduce4<<<(M_ * 64 / 4 + 255) / 256, 256, 0, stream>>>(
        (const float4*)P, (float4*)Z1, M_ * 64 / 4, 4, (size_t)M_ * 64 / 4);
    scan_tpn<<<(B_ * 64 + 255) / 256, 256, 0, stream>>>(Z1, S1, 6, TH_HID);

    // ---- layer 2 (K=64 -> 2 steps), grid 1200 blocks
    gemm_mfma64<<<dim3(150, 8, 1), 256, 0, stream>>>(
        S1, W2hi, W2lo, Zf, 64, 512, 2, 2, 0);
    scan_tpn<<<(B_ * 512 + 255) / 256, 256, 0, stream>>>(Zf, S2, 9, TH_HID);

    // ---- layer 3 (K=512 -> 16 steps), grid 1200 blocks
    gemm_mfma64<<<dim3(150, 8, 1), 256, 0, stream>>>(
        S2, W3hi, W3lo, Zf, 512, 512, 16, 16, 0);
    scan_tpn<<<(B_ * 512 + 255) / 256, 256, 0, stream>>>(Zf, S3, 9, TH_HID);

    // ---- layer 4 + readout scan
    gemm4_kernel<<<2400, 256, 0, stream>>>(S3, W4, out);
    scan4_tpn<<<5, 64, 0, stream>>>(out);
}